// Round 6
// baseline (138.427 us; speedup 1.0000x reference)
//
#include <hip/hip_runtime.h>

#define B_ 4
#define N_ 8192
#define M_ 2048
#define K_ 32
#define R2 0.16f

__device__ __forceinline__ float readlane_f(float v, int k) {
  return __int_as_float(__builtin_amdgcn_readlane(__float_as_int(v), k));
}

// ---------- fused prep: point-side + query-side in one dispatch ----------
// blocks [0, N/64):        PH[b*N+p][ch*2+{0,1}] = { afW@f , relu(mW2@relu(mW1@f+mb1)+mb2) }
// blocks [N/64, N/64+M/64): QA[b*M+m][ch] = afW@relu(qW@qf+qb)+afb ; also new_xyz -> d_out head
__global__ __launch_bounds__(256) void prep(
    const float* __restrict__ feats, const float* __restrict__ qfeat,
    const float* __restrict__ qW, const float* __restrict__ qb,
    const float* __restrict__ afW, const float* __restrict__ afb,
    const float* __restrict__ mW1, const float* __restrict__ mb1,
    const float* __restrict__ mW2, const float* __restrict__ mb2,
    const float* __restrict__ new_xyz,
    float* __restrict__ PH, float* __restrict__ QA, float* __restrict__ outhead) {
  __shared__ float xt[64][65];
  __shared__ float x2[64][65];
  int b = blockIdx.y;
  int t = threadIdx.x, lane = t & 63;
  int g = __builtin_amdgcn_readfirstlane(t >> 6);  // uniform wave id -> W rows via s_loads

  if (blockIdx.x < N_ / 64) {
    // ---- point side ----
    int p0 = blockIdx.x * 64;
    const float* src = feats + ((size_t)b * 64 + g * 16) * N_ + p0 + lane;
#pragma unroll
    for (int cc = 0; cc < 16; ++cc) xt[g * 16 + cc][lane] = src[(size_t)cc * N_];
    __syncthreads();
    float pa[16];
    {  // PA = afW @ f
#pragma unroll
      for (int cc = 0; cc < 16; ++cc) pa[cc] = 0.0f;
#pragma unroll 4
      for (int i = 0; i < 64; ++i) {
        float xv = xt[i][lane];
#pragma unroll
        for (int cc = 0; cc < 16; ++cc) pa[cc] = fmaf(afW[(g * 16 + cc) * 64 + i], xv, pa[cc]);
      }
    }
    {  // P1 = relu(mW1 f + mb1) -> LDS
      float acc[16];
#pragma unroll
      for (int cc = 0; cc < 16; ++cc) acc[cc] = mb1[g * 16 + cc];
#pragma unroll 4
      for (int i = 0; i < 64; ++i) {
        float xv = xt[i][lane];
#pragma unroll
        for (int cc = 0; cc < 16; ++cc) acc[cc] = fmaf(mW1[(g * 16 + cc) * 64 + i], xv, acc[cc]);
      }
#pragma unroll
      for (int cc = 0; cc < 16; ++cc) x2[g * 16 + cc][lane] = fmaxf(acc[cc], 0.0f);
    }
    __syncthreads();
    {  // P2 = relu(mW2 P1 + mb2); store interleaved with PA
      float h2[16];
#pragma unroll
      for (int cc = 0; cc < 16; ++cc) h2[cc] = mb2[g * 16 + cc];
#pragma unroll 4
      for (int i = 0; i < 64; ++i) {
        float xv = x2[i][lane];
#pragma unroll
        for (int cc = 0; cc < 16; ++cc) h2[cc] = fmaf(mW2[(g * 16 + cc) * 64 + i], xv, h2[cc]);
      }
      float4* o = (float4*)(PH + ((size_t)b * N_ + p0 + lane) * 128 + g * 32);
#pragma unroll
      for (int qd = 0; qd < 8; ++qd)
        o[qd] = make_float4(pa[2 * qd], fmaxf(h2[2 * qd], 0.0f),
                            pa[2 * qd + 1], fmaxf(h2[2 * qd + 1], 0.0f));
    }
  } else {
    // ---- query side ----
    int p0 = (blockIdx.x - N_ / 64) * 64;
    const float* src = qfeat + ((size_t)b * 64 + g * 16) * M_ + p0 + lane;
#pragma unroll
    for (int cc = 0; cc < 16; ++cc) xt[g * 16 + cc][lane] = src[(size_t)cc * M_];
    if (t < 192) {  // new_xyz passthrough
      size_t o = (size_t)(b * M_ + p0) * 3 + t;
      outhead[o] = new_xyz[o];
    }
    __syncthreads();
    {  // q = relu(qW f + qb) -> LDS
      float acc[16];
#pragma unroll
      for (int cc = 0; cc < 16; ++cc) acc[cc] = qb[g * 16 + cc];
#pragma unroll 4
      for (int i = 0; i < 64; ++i) {
        float xv = xt[i][lane];
#pragma unroll
        for (int cc = 0; cc < 16; ++cc) acc[cc] = fmaf(qW[(g * 16 + cc) * 64 + i], xv, acc[cc]);
      }
#pragma unroll
      for (int cc = 0; cc < 16; ++cc) x2[g * 16 + cc][lane] = fmaxf(acc[cc], 0.0f);
    }
    __syncthreads();
    {  // QA = afW q + afb
      float acc[16];
#pragma unroll
      for (int cc = 0; cc < 16; ++cc) acc[cc] = afb[g * 16 + cc];
#pragma unroll 4
      for (int i = 0; i < 64; ++i) {
        float xv = x2[i][lane];
#pragma unroll
        for (int cc = 0; cc < 16; ++cc) acc[cc] = fmaf(afW[(g * 16 + cc) * 64 + i], xv, acc[cc]);
      }
      float4* o = (float4*)(QA + ((size_t)b * M_ + p0 + lane) * 64 + g * 16);
#pragma unroll
      for (int q = 0; q < 4; ++q)
        o[q] = make_float4(acc[4 * q], acc[4 * q + 1], acc[4 * q + 2], acc[4 * q + 3]);
    }
  }
}

// ---------- ball query + aggregation; 1 wave/query, lane = channel ----------
__global__ __launch_bounds__(256) void grouper_main(
    const float* __restrict__ xyz, const float* __restrict__ new_xyz,
    const float* __restrict__ PH, const float* __restrict__ QA,
    const float* __restrict__ axW, const float* __restrict__ axb,
    const float* __restrict__ xW, const float* __restrict__ xb,
    float* __restrict__ out) {  // -> d_out + B*M*3, layout [B,80,M]
  // XCD-aware bijective swizzle (nwg=2048, 8 XCDs): each XCD gets one batch's
  // contiguous query range -> per-L2 working set ~4.2MB (one batch of PH) not 16.8MB.
  int bid = blockIdx.x;
  int newbid = (bid & 7) * (int)(gridDim.x >> 3) + (bid >> 3);
  int wid = newbid * 4 + (threadIdx.x >> 6);
  int lane = threadIdx.x & 63;
  int b = wid >> 11;
  int m = wid & (M_ - 1);
  const float* qc = new_xyz + ((size_t)b * M_ + m) * 3;
  float cx = qc[0], cy = qc[1], cz = qc[2];
  const float* xbp = xyz + (size_t)b * N_ * 3;

  // issue query-side loads early (independent of scan; latency hides under it)
  size_t qb64 = ((size_t)b * M_ + m) * 64;
  float QAm = QA[qb64 + lane];
  float ax0 = axW[lane * 3 + 0], ax1 = axW[lane * 3 + 1], ax2 = axW[lane * 3 + 2];
  float axbv = axb[lane];
  float xw0 = 0.f, xw1 = 0.f, xw2 = 0.f, xbv = 0.f;
  if (lane < 16) { xw0 = xW[lane * 3 + 0]; xw1 = xW[lane * 3 + 1]; xw2 = xW[lane * 3 + 2]; xbv = xb[lane]; }

  // --- ball query: compact (idx, gx, gy, gz, d2) of first K in-ball points into lanes 0..K-1 ---
  // software-pipelined: chunk base+64's xyz loads issue before chunk base is processed.
  int idxreg = N_ - 1;
  float gxr = 0.f, gyr = 0.f, gzr = 0.f, d2r = 0.f;
  int cnt = 0;
  float c0, c1, c2;
  {
    const float* pp = xbp + 3 * lane;
    c0 = pp[0]; c1 = pp[1]; c2 = pp[2];
  }
  int base = 0;
  while (true) {
    bool more = (base + 64) < N_;
    float n0 = 0.f, n1 = 0.f, n2 = 0.f;
    if (more) {  // wave-uniform branch
      const float* pn = xbp + 3 * (base + 64 + lane);
      n0 = pn[0]; n1 = pn[1]; n2 = pn[2];
    }
    float dx = c0 - cx, dy = c1 - cy, dz = c2 - cz;
    float d2 = dx * dx + dy * dy + dz * dz;
    bool inball = d2 < R2;
    unsigned long long mask = __ballot(inball);
    int pop = __popcll(mask);
    int before = __builtin_amdgcn_mbcnt_hi((unsigned)(mask >> 32),
                 __builtin_amdgcn_mbcnt_lo((unsigned)mask, 0));
    int pos = cnt + before;
    bool push = inball && (pos < K_);
    int dest = (push ? pos : 63) << 2;  // dummies collide on lane 63 (never taken)
    int n = base + lane;
    int rI = __builtin_amdgcn_ds_permute(dest, n);
    int rX = __builtin_amdgcn_ds_permute(dest, __float_as_int(dx));
    int rY = __builtin_amdgcn_ds_permute(dest, __float_as_int(dy));
    int rZ = __builtin_amdgcn_ds_permute(dest, __float_as_int(dz));
    int rD = __builtin_amdgcn_ds_permute(dest, __float_as_int(d2));
    int newcnt = cnt + pop;
    if ((lane >= cnt) && (lane < min(newcnt, K_))) {
      idxreg = rI; gxr = __int_as_float(rX); gyr = __int_as_float(rY);
      gzr = __int_as_float(rZ); d2r = __int_as_float(rD);
    }
    cnt = newcnt;
    if (cnt >= K_ || !more) break;
    base += 64; c0 = n0; c1 = n1; c2 = n2;
  }
  int nneigh = min(cnt, K_);
  if (nneigh == 0) {  // unreachable for this data; reference gathers point N-1
    const float* pp = xbp + 3 * (N_ - 1);
    float dx = pp[0] - cx, dy = pp[1] - cy, dz = pp[2] - cz;
    if (lane == 0) {
      idxreg = N_ - 1; gxr = dx; gyr = dy; gzr = dz;
      d2r = dx * dx + dy * dy + dz * dz;
    }
  }
  int padn = max(nneigh, 1);
  {  // pad slots >= padn with slot 0 (CUDA ball_query pad-with-first semantics)
    int i0 = __shfl(idxreg, 0);
    float x0 = __shfl(gxr, 0), y0 = __shfl(gyr, 0), z0 = __shfl(gzr, 0), d0 = __shfl(d2r, 0);
    if (lane >= padn) { idxreg = i0; gxr = x0; gyr = y0; gzr = z0; d2r = d0; }
  }
  float idn_mask = (nneigh > 0) ? 1.0f : 0.0f;

  // per-lane reciprocal distance for the slot this lane holds (hoisted transcendentals)
  float rslot = __builtin_amdgcn_rcpf(__builtin_amdgcn_sqrtf(d2r) + 1e-8f);
  if (nneigh > 0 && lane >= nneigh && lane < K_) rslot = __builtin_huge_valf();  // r/idn=inf (unreachable path)
  // Rsum = sum of r over the K slots (wave tree-reduce; lanes >= K contribute 0)
  float Rsum;
  {
    float s = (lane < K_) ? rslot : 0.0f;
    s += __shfl_xor(s, 1);  s += __shfl_xor(s, 2);  s += __shfl_xor(s, 4);
    s += __shfl_xor(s, 8);  s += __shfl_xor(s, 16); s += __shfl_xor(s, 32);
    Rsum = s;
  }

  const float* PHb = PH + (size_t)b * N_ * 128;

  // k-loop: 2 groups of 16; hoisted index readlanes, 16 gathers in flight,
  // split accumulators to break the serial FMA chain.
  float accS0 = 0.f, accS1 = 0.f, nxmax = 0.f;
#pragma unroll
  for (int kg = 0; kg < 2; ++kg) {
    int ns[16];
    float2 v[16];
#pragma unroll
    for (int j = 0; j < 16; ++j)
      ns[j] = __builtin_amdgcn_readlane(idxreg, kg * 16 + j);  // uniform -> SGPR
#pragma unroll
    for (int j = 0; j < 16; ++j)
      v[j] = *(const float2*)(PHb + (size_t)ns[j] * 128 + lane * 2);  // coalesced dwordx2
#pragma unroll
    for (int j = 0; j < 16; ++j) {
      int k = kg * 16 + j;
      float gx = readlane_f(gxr, k);
      float gy = readlane_f(gyr, k);
      float gz = readlane_f(gzr, k);
      float rr = readlane_f(rslot, k);
      float fd = fmaxf(QAm - v[j].x, 0.f);                                       // relu(afW@(q-g)+afb)
      float sd = fmaxf(fmaf(ax0, gx, fmaf(ax1, gy, fmaf(ax2, gz, axbv))), 0.f);  // relu(axW@g+axb)
      float term = rr * (v[j].y * fd * sd);
      if (j & 1) accS1 += term; else accS0 += term;
      float nv = fmaxf(fmaf(xw0, gx, fmaf(xw1, gy, fmaf(xw2, gz, xbv))), 0.f);
      nxmax = fmaxf(nxmax, nv);
    }
  }
  float nf = ((accS0 + accS1) / Rsum) * idn_mask;
  float* ob = out + (size_t)b * 80 * M_;
  ob[(size_t)(16 + lane) * M_ + m] = nf;
  if (lane < 16) ob[(size_t)lane * M_ + m] = nxmax;
}

extern "C" void kernel_launch(void* const* d_in, const int* in_sizes, int n_in,
                              void* d_out, int out_size, void* d_ws, size_t ws_size,
                              hipStream_t stream) {
  const float* xyz   = (const float*)d_in[0];
  const float* nxyz  = (const float*)d_in[1];
  const float* feats = (const float*)d_in[2];
  const float* qfeat = (const float*)d_in[3];
  const float* qW  = (const float*)d_in[4];
  const float* qb  = (const float*)d_in[5];
  const float* afW = (const float*)d_in[6];
  const float* afb = (const float*)d_in[7];
  const float* axW = (const float*)d_in[8];
  const float* axb = (const float*)d_in[9];
  const float* mW1 = (const float*)d_in[10];
  const float* mb1 = (const float*)d_in[11];
  const float* mW2 = (const float*)d_in[12];
  const float* mb2 = (const float*)d_in[13];
  const float* xW  = (const float*)d_in[14];
  const float* xb  = (const float*)d_in[15];

  float* ws = (float*)d_ws;
  size_t off = 0;
  float* PH = ws + off; off += (size_t)B_ * N_ * 128;  // interleaved {PA, P2}
  float* QA = ws + off; off += (size_t)B_ * M_ * 64;
  if (ws_size < off * sizeof(float)) return;  // fail loudly rather than corrupt

  float* outhead = (float*)d_out;  // new_xyz passthrough at d_out[0 : B*M*3]
  prep<<<dim3(N_ / 64 + M_ / 64, B_), 256, 0, stream>>>(
      feats, qfeat, qW, qb, afW, afb, mW1, mb1, mW2, mb2, nxyz, PH, QA, outhead);

  float* out_main = (float*)d_out + (size_t)B_ * M_ * 3;
  grouper_main<<<B_ * M_ / 4, 256, 0, stream>>>(xyz, nxyz, PH, QA,
                                                axW, axb, xW, xb, out_main);
}